// Round 11
// baseline (343.846 us; speedup 1.0000x reference)
//
#include <hip/hip_runtime.h>
#include <hip/hip_bf16.h>
#include <math.h>

#define GX 128
#define GY 128
#define GZ 16
#define CELLS (GX*GY*GZ)   // 262144
#define NCELLT (NB*CELLS)  // 524288
#define NB 2
#define NV 100000
#define NM (NB*NV)         // 200000
#define NN 8192
#define NK 8
#define NC 64
#define EPSV 1e-5f
#define TM 256             // conv row tile (64 rows per wave)
#define NTILE 98           // tiles per XCD slice (8*98*256 = 200704 >= NM)
#define NBLK (8*NTILE)     // 784 conv blocks
#define NMT (NBLK*TM)      // 200704 padded rows
#define KPH 7              // k-offsets per LDS phase (4 phases, K padded to 28)

typedef __attribute__((ext_vector_type(8))) short short8;    // 8 bf16
typedef __attribute__((ext_vector_type(4))) float floatx4;   // MFMA C/D

__device__ __forceinline__ float bf2f(unsigned short u) {
    unsigned int x = ((unsigned int)u) << 16;
    return __builtin_bit_cast(float, x);
}
__device__ __forceinline__ unsigned short f2bf(float f) {
    unsigned int u = __builtin_bit_cast(unsigned int, f);
    return (unsigned short)((u + 0x7fffu + ((u >> 16) & 1u)) >> 16);
}

// ---------------- init: grid_old = -1, stats = 0, featA zero-row ----------------
__global__ void k_init(int* __restrict__ grid, float* __restrict__ stats,
                       unsigned short* __restrict__ featA) {
    int i = blockIdx.x * 256 + threadIdx.x;
    if (i < NCELLT) grid[i] = -1;
    else if (i < NCELLT + 512) stats[i - NCELLT] = 0.f;
    else if (i < NCELLT + 512 + 64) featA[(size_t)NM * 64 + (i - NCELLT - 512)] = 0;
}

// ---------------- scatter voxel rows into grid_old (original ids) ----------------
__global__ void k_scatter(const int* __restrict__ coords, int* __restrict__ grid) {
    int gid = blockIdx.x * 256 + threadIdx.x;
    if (gid >= NM) return;
    int b = (gid >= NV) ? 1 : 0;
    int x = coords[gid * 3 + 0];
    int y = coords[gid * 3 + 1];
    int z = coords[gid * 3 + 2];
    grid[((b * GX + x) * GY + y) * GZ + z] = gid;
}

// ---------------- spatial sort step 1: per-block occupancy counts ----------------
__global__ void k_count(const int* __restrict__ grid, int* __restrict__ bcnt) {
    __shared__ int wt[4];
    int t = threadIdx.x;
    int occ = (grid[blockIdx.x * 256 + t] >= 0) ? 1 : 0;
    int w = t >> 6;
    unsigned long long m = __ballot(occ);
    if ((t & 63) == 0) wt[w] = __popcll(m);
    __syncthreads();
    if (t == 0) bcnt[blockIdx.x] = wt[0] + wt[1] + wt[2] + wt[3];
}

// ---------------- spatial sort step 2: scan 2048 block counts ----------------
__global__ void k_scan2048(const int* __restrict__ bcnt, int* __restrict__ boff) {
    __shared__ int s[256];
    int t = threadIdx.x;
    int v[8], sum = 0;
    #pragma unroll
    for (int j = 0; j < 8; ++j) {
        int x = bcnt[t * 8 + j];
        v[j] = sum;          // exclusive within chunk
        sum += x;
    }
    s[t] = sum;
    __syncthreads();
    for (int off = 1; off < 256; off <<= 1) {
        int x = (t >= off) ? s[t - off] : 0;
        __syncthreads();
        s[t] += x;
        __syncthreads();
    }
    int excl = s[t] - sum;
    #pragma unroll
    for (int j = 0; j < 8; ++j) boff[t * 8 + j] = excl + v[j];
}

// ---------------- spatial sort step 3: assign new ids ----------------
__global__ void k_assign(const int* __restrict__ gold, const int* __restrict__ boff,
                         int* __restrict__ gnew, int* __restrict__ perm,
                         int* __restrict__ scell) {
    __shared__ int wt[4];
    int t = threadIdx.x;
    int cell = blockIdx.x * 256 + t;
    int old = gold[cell];
    int occ = (old >= 0) ? 1 : 0;
    int w = t >> 6, lane = t & 63;
    unsigned long long m = __ballot(occ);
    int lp = __popcll(m & ((1ULL << lane) - 1ULL));
    if (lane == 63) wt[w] = lp + occ;
    __syncthreads();
    int wbase = 0;
    #pragma unroll
    for (int j = 0; j < 4; ++j) if (j < w) wbase += wt[j];
    int nid = boff[blockIdx.x] + wbase + lp;
    if (occ) {
        gnew[cell] = nid;
        perm[nid] = old;
        scell[nid] = cell;
    } else {
        gnew[cell] = -1;
    }
}

// ---------------- fallback id: sorted id of ORIGINAL row 0 (reference max(idx,0)) --
__global__ void k_fb(const int* __restrict__ vcoords, const int* __restrict__ gnew,
                     int* __restrict__ fbp) {
    if (threadIdx.x == 0 && blockIdx.x == 0) {
        int cell = (vcoords[0] * GY + vcoords[1]) * GZ + vcoords[2];  // batch 0
        fbp[0] = gnew[cell];
    }
}

// ---------------- neighbor table: nid[k][m] (zero-row folded in) ----------------
// Computed ONCE, shared by both conv layers.  k = 27 dummy -> NM (zero row).
__global__ void k_nbr(const int* __restrict__ scell, const int* __restrict__ gnew,
                      int* __restrict__ nid) {
    int m = blockIdx.x * 256 + threadIdx.x;
    if (m >= NMT) return;
    int cell = (m < NM) ? scell[m] : -1;
    int x = 0, y = 0, z = 0;
    if (cell >= 0) { x = (cell >> 11) & 127; y = (cell >> 4) & 127; z = cell & 15; }
    #pragma unroll
    for (int k = 0; k < 28; ++k) {
        int ni = NM;
        if (k < 27 && cell >= 0) {
            int dx = k / 9 - 1, dy = (k / 3) % 3 - 1, dz = k % 3 - 1;
            int nx = x + dx, ny = y + dy, nz = z + dz;
            if (nx >= 0 && nx < GX && ny >= 0 && ny < GY && nz >= 0 && nz < GZ) {
                int g = gnew[cell + dx * (GY * GZ) + dy * GZ + dz];
                ni = (g < 0) ? NM : g;
            }
        }
        nid[(size_t)k * NMT + m] = ni;
    }
}

// ---------------- weight prep: bf16, MFMA-fragment order, K padded to 28 --------
__global__ void k_wprep(const float* __restrict__ W1, const float* __restrict__ W2,
                        unsigned short* __restrict__ Wt1, unsigned short* __restrict__ Wt2) {
    int e = blockIdx.x * 256 + threadIdx.x;  // 28*8*64 = 14336 frag-lanes
    if (e >= 28 * 512) return;
    int lane = e & 63;
    int fr = (e >> 6) & 7;
    int k = e >> 9;
    int ct = fr >> 1, ks = fr & 1;
    int quad = lane >> 4, n16 = lane & 15;
    int co = ct * 16 + n16;
    #pragma unroll
    for (int j = 0; j < 8; ++j) {
        int ci = ks * 32 + quad * 8 + j;
        unsigned short w1 = 0, w2 = 0;
        if (k < 27) {
            w1 = f2bf(W1[(k << 12) + ci * 64 + co]);
            w2 = f2bf(W2[(k << 12) + ci * 64 + co]);
        }
        Wt1[(size_t)e * 8 + j] = w1;
        Wt2[(size_t)e * 8 + j] = w2;
    }
}

// ---------------- permute + fp32 -> bf16 (sorted feature build) ----------------
__global__ void k_tobf16s(const float* __restrict__ in, const int* __restrict__ perm,
                          unsigned short* __restrict__ out) {
    int i = blockIdx.x * 256 + threadIdx.x;   // over NM*8 (8 channels each)
    if (i >= NM * 8) return;
    int mrow = i >> 3, part = i & 7;
    int src = perm[mrow];
    const float4* s = (const float4*)(in + (size_t)src * 64 + part * 8);
    float4 a = s[0], b = s[1];
    ushort4 lo, hi;
    lo.x = f2bf(a.x); lo.y = f2bf(a.y); lo.z = f2bf(a.z); lo.w = f2bf(a.w);
    hi.x = f2bf(b.x); hi.y = f2bf(b.y); hi.z = f2bf(b.z); hi.w = f2bf(b.w);
    ushort4* d = (ushort4*)(out + (size_t)mrow * 64 + part * 8);
    d[0] = lo; d[1] = hi;
}

// ---------------- submanifold conv 3x3x3, C=64->64, bf16 MFMA, sorted space ----
// 64 rows/wave, B via per-phase LDS stage (57 KB).  Gather indices come from the
// precomputed nid table: loaded into registers at phase top (28 coalesced dwords)
// -> zero LDS/addr dependency in the k-loop.  A ring depth 3 (prefetch distance
// 2 iters ~600 cyc > L2 latency), sched_barrier-pinned.
__global__ __launch_bounds__(256, 2) void k_conv(
    const unsigned short* __restrict__ feats, const int* __restrict__ nid,
    const unsigned short* __restrict__ Wt,
    unsigned short* __restrict__ out, float* __restrict__ gsum, float* __restrict__ gsq)
{
    __shared__ unsigned short s_b[KPH * 4096];   // 57344 B (reused for BN reduction)

    int tid = threadIdx.x;
    int bid = blockIdx.x;
    int tile = (bid & 7) * NTILE + (bid >> 3);   // XCD swizzle
    int m0 = tile * TM;

    int w = tid >> 6, lane = tid & 63;
    int quad = lane >> 4, n16 = lane & 15;
    const unsigned short* fq = feats + quad * 8;
    const int* nbase = nid + m0 + w * 64 + n16;

    short8 afr[3][8];     // A ring, depth 3: [ring][rt*2+ks]

    auto issueA = [&](const int* nr, short8* af) {
        #pragma unroll
        for (int rt = 0; rt < 4; ++rt) {
            const unsigned short* r0 = fq + (size_t)nr[rt] * 64;
            af[rt * 2 + 0] = *(const short8*)(r0);
            af[rt * 2 + 1] = *(const short8*)(r0 + 32);
        }
    };

    floatx4 acc[4][4];
    #pragma unroll
    for (int rt = 0; rt < 4; ++rt)
        #pragma unroll
        for (int ct = 0; ct < 4; ++ct)
            acc[rt][ct] = (floatx4){0.f, 0.f, 0.f, 0.f};

    const uint4* wt4 = (const uint4*)Wt;

    for (int ph = 0; ph < 4; ++ph) {
        int k0 = ph * KPH;
        __syncthreads();   // previous phase's s_b fully consumed

        // stage B for this phase: 14 x 16 B contiguous per thread
        uint4 breg[KPH * 2];
        #pragma unroll
        for (int i = 0; i < KPH * 2; ++i)
            breg[i] = wt4[(size_t)k0 * 512 + i * 256 + tid];

        // gather indices for the whole phase -> registers (coalesced dwords)
        int nidr[KPH][4];
        #pragma unroll
        for (int j = 0; j < KPH; ++j)
            #pragma unroll
            for (int rt = 0; rt < 4; ++rt)
                nidr[j][rt] = nbase[(size_t)(k0 + j) * NMT + rt * 16];

        #pragma unroll
        for (int i = 0; i < KPH * 2; ++i)
            ((uint4*)s_b)[i * 256 + tid] = breg[i];

        // A prologue for this phase (drained by the barrier; ready at j=0)
        issueA(nidr[0], afr[0]);
        issueA(nidr[1], afr[1]);
        __syncthreads();

        #pragma unroll
        for (int j = 0; j < KPH; ++j) {
            if (j + 2 < KPH) issueA(nidr[j + 2], afr[(j + 2) % 3]);
            __builtin_amdgcn_sched_barrier(0);   // A loads stay above MFMAs

            const unsigned short* bb = s_b + j * 4096;
            short8 bfr[8];
            #pragma unroll
            for (int fr = 0; fr < 8; ++fr)
                bfr[fr] = *(const short8*)(bb + fr * 512 + lane * 8);

            const short8* ac = afr[j % 3];
            #pragma unroll
            for (int ks = 0; ks < 2; ++ks)
                #pragma unroll
                for (int rt = 0; rt < 4; ++rt)
                    #pragma unroll
                    for (int ct = 0; ct < 4; ++ct)
                        acc[rt][ct] = __builtin_amdgcn_mfma_f32_16x16x32_bf16(
                            ac[rt * 2 + ks], bfr[ct * 2 + ks], acc[rt][ct], 0, 0, 0);
            __builtin_amdgcn_sched_barrier(0);   // MFMAs stay above next A loads
        }
    }

    // store bf16 conv output.  C/D layout: col = lane&15, row = quad*4 + reg
    #pragma unroll
    for (int rt = 0; rt < 4; ++rt) {
        int rbase = m0 + w * 64 + rt * 16 + quad * 4;
        #pragma unroll
        for (int rg = 0; rg < 4; ++rg) {
            int m = rbase + rg;
            if (m < NM) {
                #pragma unroll
                for (int ct = 0; ct < 4; ++ct)
                    out[(size_t)m * 64 + ct * 16 + n16] = f2bf(acc[rt][ct][rg]);
            }
        }
    }

    // BN stats from fp32 accumulators (pad rows gather only zero-row -> exact 0)
    float ps[4], pq[4];
    #pragma unroll
    for (int ct = 0; ct < 4; ++ct) { ps[ct] = 0.f; pq[ct] = 0.f; }
    #pragma unroll
    for (int rt = 0; rt < 4; ++rt)
        #pragma unroll
        for (int ct = 0; ct < 4; ++ct)
            #pragma unroll
            for (int rg = 0; rg < 4; ++rg) {
                float v = acc[rt][ct][rg];
                ps[ct] += v;
                pq[ct] += v * v;
            }
    #pragma unroll
    for (int ct = 0; ct < 4; ++ct) {
        ps[ct] += __shfl_xor(ps[ct], 16);
        ps[ct] += __shfl_xor(ps[ct], 32);
        pq[ct] += __shfl_xor(pq[ct], 16);
        pq[ct] += __shfl_xor(pq[ct], 32);
    }
    __syncthreads();
    float* red = (float*)s_b;
    if (lane < 16) {
        #pragma unroll
        for (int ct = 0; ct < 4; ++ct) {
            red[w * 64 + ct * 16 + n16]       = ps[ct];
            red[256 + w * 64 + ct * 16 + n16] = pq[ct];
        }
    }
    __syncthreads();
    if (tid < 64) {
        float ts = 0.f, tq = 0.f;
        #pragma unroll
        for (int ww = 0; ww < 4; ++ww) {
            ts += red[ww * 64 + tid];
            tq += red[256 + ww * 64 + tid];
        }
        atomicAdd(gsum + tid, ts);
        atomicAdd(gsq + tid, tq);
    }
}

// ---------------- BN coefficients ----------------
__global__ void k_bncoef(const float* __restrict__ gsum, const float* __restrict__ gsq,
                         const float* __restrict__ gamma, const float* __restrict__ beta,
                         float* __restrict__ coef) {
    int c = threadIdx.x;
    if (c >= 64) return;
    float mu = gsum[c] / (float)NM;
    float var = gsq[c] / (float)NM - mu * mu;
    float scale = gamma[c] / sqrtf(var + EPSV);
    coef[c] = scale;
    coef[64 + c] = beta[c] - mu * scale;
}

// ---------------- BN apply + ReLU (bf16 -> bf16) ----------------
__global__ void k_bnapply(const unsigned short* __restrict__ in, const float* __restrict__ coef,
                          unsigned short* __restrict__ out) {
    int i = blockIdx.x * 256 + threadIdx.x;  // over NM*8 groups of 8 bf16
    if (i >= NM * 8) return;
    int c8 = (i & 7) * 8;
    uint4 v = ((const uint4*)in)[i];
    unsigned int vv[4] = {v.x, v.y, v.z, v.w};
    unsigned int oo[4];
    #pragma unroll
    for (int j = 0; j < 4; ++j) {
        int c = c8 + j * 2;
        float lo = bf2f((unsigned short)(vv[j] & 0xffffu));
        float hi = bf2f((unsigned short)(vv[j] >> 16));
        lo = fmaxf(lo * coef[c]     + coef[64 + c],     0.f);
        hi = fmaxf(hi * coef[c + 1] + coef[64 + c + 1], 0.f);
        oo[j] = (unsigned int)f2bf(lo) | ((unsigned int)f2bf(hi) << 16);
    }
    uint4 o = {oo[0], oo[1], oo[2], oo[3]};
    ((uint4*)out)[i] = o;
}

// ---------------- keypoint sampling + fused BN2/ReLU + projection ----------------
__global__ __launch_bounds__(256) void k_sample(
    const float* __restrict__ kp, const float* __restrict__ query,
    const unsigned short* __restrict__ conv2, const float* __restrict__ coef2,
    const int* __restrict__ grid, const int* __restrict__ fbp,
    const float* __restrict__ projW, const float* __restrict__ projB,
    float* __restrict__ out_fused, float* __restrict__ out_vi)
{
    __shared__ float s_pw[64 * 65];
    __shared__ float s_mean[4][64];
    __shared__ int   s_idx[4][8];

    int tid = threadIdx.x;
    for (int e = tid; e < 4096; e += 256) {
        int co = e >> 6, c = e & 63;
        s_pw[co * 65 + c] = projW[e];
    }

    int w = tid >> 6, lane = tid & 63;
    int row = blockIdx.x * 4 + w;   // < 16384
    int b = row >> 13;              // NN = 8192
    float sc = coef2[lane];
    float sh = coef2[64 + lane];
    int fb = fbp[0];                // sorted id of original row 0
    __syncthreads();

    if (lane < 8) {
        int kk = lane;
        const float* kpp = kp + ((size_t)row * 8 + kk) * 3;
        int qx = min(max((int)(kpp[0] * 2.0f), 0), GX - 1);
        int qy = min(max((int)(kpp[1] * 2.0f), 0), GY - 1);
        int qz = min(max((int)(kpp[2] * 2.0f), 0), GZ - 1);
        s_idx[w][kk] = grid[((b * GX + qx) * GY + qy) * GZ + qz];
        float4 vi = make_float4((float)b, (float)qx, (float)qy, (float)qz);
        *(float4*)(out_vi + ((size_t)row * 8 + kk) * 4) = vi;
    }
    __syncthreads();

    float acc = 0.f;
    #pragma unroll
    for (int kk = 0; kk < 8; ++kk) {
        int gi = s_idx[w][kk];
        gi = gi < 0 ? fb : gi;
        float v = bf2f(conv2[(size_t)gi * 64 + lane]);
        acc += fmaxf(v * sc + sh, 0.f);      // fused BN2 + ReLU
    }
    float mean = acc * 0.125f + query[(size_t)row * 64 + lane];
    s_mean[w][lane] = mean;
    __syncthreads();

    float f = projB[lane];
    const float* pwr = s_pw + lane * 65;
    const float* mv = s_mean[w];
    #pragma unroll 8
    for (int c = 0; c < 64; ++c) f += mv[c] * pwr[c];
    out_fused[(size_t)row * 64 + lane] = f;
}

// ---------------- launch ----------------
extern "C" void kernel_launch(void* const* d_in, const int* in_sizes, int n_in,
                              void* d_out, int out_size, void* d_ws, size_t ws_size,
                              hipStream_t stream) {
    const float* keypoints = (const float*)d_in[0];
    const float* query     = (const float*)d_in[1];
    const float* vfeat     = (const float*)d_in[2];
    const int*   vcoords   = (const int*)d_in[3];
    const float* W1        = (const float*)d_in[4];
    const float* g1        = (const float*)d_in[5];
    const float* b1        = (const float*)d_in[6];
    const float* W2        = (const float*)d_in[7];
    const float* g2        = (const float*)d_in[8];
    const float* b2        = (const float*)d_in[9];
    const float* pW        = (const float*)d_in[10];
    const float* pb        = (const float*)d_in[11];

    char* ws = (char*)d_ws;
    int*            gold  = (int*)ws;                          // 2,097,152 B
    int*            gnew  = (int*)(ws + 2097152);              // 2,097,152 B
    float*          stats = (float*)(ws + 4194304);            // 2048 B
    int*            fbp   = (int*)(ws + 4196352);              // 256 B
    int*            bcnt  = (int*)(ws + 4196608);              // 8192 B
    int*            boff  = (int*)(ws + 4204800);              // 8192 B
    int*            perm  = (int*)(ws + 4212992);              // 800,000 B
    int*            scell = (int*)(ws + 5012992);              // 800,000 B
    unsigned short* Wt1   = (unsigned short*)(ws + 5812992);   // 229,376 B (28 k's)
    unsigned short* Wt2   = (unsigned short*)(ws + 6042368);   // 229,376 B
    unsigned short* featA = (unsigned short*)(ws + 6271744);   // (NM+1)*128 B -> 25,600,256
    int*            nidt  = (int*)(ws + 31872000);             // 28*NMT*4 = 22,478,848 B
    unsigned short* convo = (unsigned short*)(ws + 54350848);  // 25,600,000 B (ends ~80 MB)

    float* sum1 = stats,       *sq1 = stats + 64,  *coef1 = stats + 128;
    float* sum2 = stats + 256, *sq2 = stats + 320, *coef2 = stats + 384;

    int initN = NCELLT + 512 + 64;
    k_init<<<(initN + 255) / 256, 256, 0, stream>>>(gold, stats, featA);
    k_scatter<<<(NM + 255) / 256, 256, 0, stream>>>(vcoords, gold);

    // spatial renumbering: count -> scan -> assign -> fallback id -> neighbor table
    k_count<<<NCELLT / 256, 256, 0, stream>>>(gold, bcnt);
    k_scan2048<<<1, 256, 0, stream>>>(bcnt, boff);
    k_assign<<<NCELLT / 256, 256, 0, stream>>>(gold, boff, gnew, perm, scell);
    k_fb<<<1, 64, 0, stream>>>(vcoords, gnew, fbp);
    k_nbr<<<NMT / 256, 256, 0, stream>>>(scell, gnew, nidt);

    k_wprep<<<(28 * 512 + 255) / 256, 256, 0, stream>>>(W1, W2, Wt1, Wt2);
    k_tobf16s<<<(NM * 8 + 255) / 256, 256, 0, stream>>>(vfeat, perm, featA);

    k_conv<<<NBLK, 256, 0, stream>>>(featA, nidt, Wt1, convo, sum1, sq1);
    k_bncoef<<<1, 64, 0, stream>>>(sum1, sq1, g1, b1, coef1);
    k_bnapply<<<(NM * 8 + 255) / 256, 256, 0, stream>>>(convo, coef1, featA);

    k_conv<<<NBLK, 256, 0, stream>>>(featA, nidt, Wt2, convo, sum2, sq2);
    k_bncoef<<<1, 64, 0, stream>>>(sum2, sq2, g2, b2, coef2);

    float* out_fused = (float*)d_out;
    float* out_vi = out_fused + (size_t)NB * NN * NC;  // 1,048,576 floats
    k_sample<<<(NB * NN) / 4, 256, 0, stream>>>(keypoints, query, convo, coef2, gnew, fbp,
                                                pW, pb, out_fused, out_vi);
}

// Round 12
// 325.018 us; speedup vs baseline: 1.0579x; 1.0579x over previous
//
#include <hip/hip_runtime.h>
#include <hip/hip_bf16.h>
#include <math.h>

#define GX 128
#define GY 128
#define GZ 16
#define CELLS (GX*GY*GZ)   // 262144
#define NCELLT (NB*CELLS)  // 524288
#define NB 2
#define NV 100000
#define NM (NB*NV)         // 200000
#define NN 8192
#define NK 8
#define NC 64
#define EPSV 1e-5f
#define TM 128             // conv row tile (32 rows per wave)
#define NTILE 196          // tiles per XCD slice (8*196*128 = 200704 >= NM)
#define NBLK (8*NTILE)     // 1568 conv blocks
#define NMT (NBLK*TM)      // 200704 padded rows
#define KPH 4              // k-offsets per LDS phase (7 phases, K padded to 28)

typedef __attribute__((ext_vector_type(8))) short short8;    // 8 bf16
typedef __attribute__((ext_vector_type(4))) float floatx4;   // MFMA C/D

__device__ __forceinline__ float bf2f(unsigned short u) {
    unsigned int x = ((unsigned int)u) << 16;
    return __builtin_bit_cast(float, x);
}
__device__ __forceinline__ unsigned short f2bf(float f) {
    unsigned int u = __builtin_bit_cast(unsigned int, f);
    return (unsigned short)((u + 0x7fffu + ((u >> 16) & 1u)) >> 16);
}

// ---------------- init: grid_old = -1, stats = 0, featA zero-row ----------------
__global__ void k_init(int* __restrict__ grid, float* __restrict__ stats,
                       unsigned short* __restrict__ featA) {
    int i = blockIdx.x * 256 + threadIdx.x;
    if (i < NCELLT) grid[i] = -1;
    else if (i < NCELLT + 512) stats[i - NCELLT] = 0.f;
    else if (i < NCELLT + 512 + 64) featA[(size_t)NM * 64 + (i - NCELLT - 512)] = 0;
}

// ---------------- scatter voxel rows into grid_old (original ids) ----------------
__global__ void k_scatter(const int* __restrict__ coords, int* __restrict__ grid) {
    int gid = blockIdx.x * 256 + threadIdx.x;
    if (gid >= NM) return;
    int b = (gid >= NV) ? 1 : 0;
    int x = coords[gid * 3 + 0];
    int y = coords[gid * 3 + 1];
    int z = coords[gid * 3 + 2];
    grid[((b * GX + x) * GY + y) * GZ + z] = gid;
}

// ---------------- spatial sort step 1: per-block occupancy counts ----------------
__global__ void k_count(const int* __restrict__ grid, int* __restrict__ bcnt) {
    __shared__ int wt[4];
    int t = threadIdx.x;
    int occ = (grid[blockIdx.x * 256 + t] >= 0) ? 1 : 0;
    int w = t >> 6;
    unsigned long long m = __ballot(occ);
    if ((t & 63) == 0) wt[w] = __popcll(m);
    __syncthreads();
    if (t == 0) bcnt[blockIdx.x] = wt[0] + wt[1] + wt[2] + wt[3];
}

// ---------------- spatial sort step 2: scan 2048 block counts ----------------
__global__ void k_scan2048(const int* __restrict__ bcnt, int* __restrict__ boff) {
    __shared__ int s[256];
    int t = threadIdx.x;
    int v[8], sum = 0;
    #pragma unroll
    for (int j = 0; j < 8; ++j) {
        int x = bcnt[t * 8 + j];
        v[j] = sum;          // exclusive within chunk
        sum += x;
    }
    s[t] = sum;
    __syncthreads();
    for (int off = 1; off < 256; off <<= 1) {
        int x = (t >= off) ? s[t - off] : 0;
        __syncthreads();
        s[t] += x;
        __syncthreads();
    }
    int excl = s[t] - sum;
    #pragma unroll
    for (int j = 0; j < 8; ++j) boff[t * 8 + j] = excl + v[j];
}

// ---------------- spatial sort step 3: assign new ids ----------------
__global__ void k_assign(const int* __restrict__ gold, const int* __restrict__ boff,
                         int* __restrict__ gnew, int* __restrict__ perm,
                         int* __restrict__ scell) {
    __shared__ int wt[4];
    int t = threadIdx.x;
    int cell = blockIdx.x * 256 + t;
    int old = gold[cell];
    int occ = (old >= 0) ? 1 : 0;
    int w = t >> 6, lane = t & 63;
    unsigned long long m = __ballot(occ);
    int lp = __popcll(m & ((1ULL << lane) - 1ULL));
    if (lane == 63) wt[w] = lp + occ;
    __syncthreads();
    int wbase = 0;
    #pragma unroll
    for (int j = 0; j < 4; ++j) if (j < w) wbase += wt[j];
    int nid = boff[blockIdx.x] + wbase + lp;
    if (occ) {
        gnew[cell] = nid;
        perm[nid] = old;
        scell[nid] = cell;
    } else {
        gnew[cell] = -1;
    }
}

// ---------------- neighbor table (+fallback id): nid[k][m], zero-row folded ----
// Computed ONCE, shared by both conv layers.  k = 27 dummy -> NM (zero row).
// fbp[0] = sorted id of ORIGINAL row 0 (reference's feats[max(idx,0)] fallback).
__global__ void k_nbr(const int* __restrict__ scell, const int* __restrict__ gnew,
                      const int* __restrict__ vcoords,
                      int* __restrict__ nid, int* __restrict__ fbp) {
    if (blockIdx.x == 0 && threadIdx.x == 0) {
        int cell0 = (vcoords[0] * GY + vcoords[1]) * GZ + vcoords[2];  // batch 0
        fbp[0] = gnew[cell0];
    }
    int m = blockIdx.x * 256 + threadIdx.x;
    if (m >= NMT) return;
    int cell = (m < NM) ? scell[m] : -1;
    int x = 0, y = 0, z = 0;
    if (cell >= 0) { x = (cell >> 11) & 127; y = (cell >> 4) & 127; z = cell & 15; }
    #pragma unroll
    for (int k = 0; k < 28; ++k) {
        int ni = NM;
        if (k < 27 && cell >= 0) {
            int dx = k / 9 - 1, dy = (k / 3) % 3 - 1, dz = k % 3 - 1;
            int nx = x + dx, ny = y + dy, nz = z + dz;
            if (nx >= 0 && nx < GX && ny >= 0 && ny < GY && nz >= 0 && nz < GZ) {
                int g = gnew[cell + dx * (GY * GZ) + dy * GZ + dz];
                ni = (g < 0) ? NM : g;
            }
        }
        nid[(size_t)k * NMT + m] = ni;
    }
}

// ---------------- merged prep: weight transpose->bf16 + feature permute->bf16 ----
// blocks [0,56): Wt1/Wt2 in MFMA-fragment order (K padded to 28, k=27 zero).
// blocks [56,...): featA[mrow] = bf16(vfeat[perm[mrow]]).
__global__ void k_prep(const float* __restrict__ W1, const float* __restrict__ W2,
                       const float* __restrict__ vfeat, const int* __restrict__ perm,
                       unsigned short* __restrict__ Wt1, unsigned short* __restrict__ Wt2,
                       unsigned short* __restrict__ featA) {
    int bid = blockIdx.x;
    if (bid < 56) {
        int e = bid * 256 + threadIdx.x;    // < 14336 = 28*512
        int lane = e & 63;
        int fr = (e >> 6) & 7;
        int k = e >> 9;
        int ct = fr >> 1, ks = fr & 1;
        int quad = lane >> 4, n16 = lane & 15;
        int co = ct * 16 + n16;
        #pragma unroll
        for (int j = 0; j < 8; ++j) {
            int ci = ks * 32 + quad * 8 + j;
            unsigned short w1 = 0, w2 = 0;
            if (k < 27) {
                w1 = f2bf(W1[(k << 12) + ci * 64 + co]);
                w2 = f2bf(W2[(k << 12) + ci * 64 + co]);
            }
            Wt1[(size_t)e * 8 + j] = w1;
            Wt2[(size_t)e * 8 + j] = w2;
        }
    } else {
        int i = (bid - 56) * 256 + threadIdx.x;   // over NM*8
        if (i >= NM * 8) return;
        int mrow = i >> 3, part = i & 7;
        int src = perm[mrow];
        const float4* s = (const float4*)(vfeat + (size_t)src * 64 + part * 8);
        float4 a = s[0], b = s[1];
        ushort4 lo, hi;
        lo.x = f2bf(a.x); lo.y = f2bf(a.y); lo.z = f2bf(a.z); lo.w = f2bf(a.w);
        hi.x = f2bf(b.x); hi.y = f2bf(b.y); hi.z = f2bf(b.z); hi.w = f2bf(b.w);
        ushort4* d = (ushort4*)(featA + (size_t)mrow * 64 + part * 8);
        d[0] = lo; d[1] = hi;
    }
}

// ---------------- submanifold conv 3x3x3, C=64->64, bf16 MFMA, sorted space ----
// Occupancy-first variant: 32 rows/wave (32 AGPR acc), KPH=4 -> 32 KB LDS,
// target 3 waves/SIMD (12 waves/CU, 3 blocks/CU).  B staged per phase in LDS
// (shared by 4 waves x 4 iters); A gathers direct-to-register ring depth 3
// (distance 2, sched_barrier-pinned); nid indices ring-prefetched a full
// phase ahead so phase tops only pay the A drain.
__global__ __launch_bounds__(256, 3) void k_conv(
    const unsigned short* __restrict__ feats, const int* __restrict__ nid,
    const unsigned short* __restrict__ Wt,
    unsigned short* __restrict__ out, float* __restrict__ gsum, float* __restrict__ gsq)
{
    __shared__ unsigned short s_b[KPH * 4096];   // 32768 B (reused for BN reduction)

    int tid = threadIdx.x;
    int bid = blockIdx.x;
    int tile = (bid & 7) * NTILE + (bid >> 3);   // XCD swizzle
    int m0 = tile * TM;

    int w = tid >> 6, lane = tid & 63;
    int quad = lane >> 4, n16 = lane & 15;
    const unsigned short* fq = feats + quad * 8;
    const int* nbase = nid + m0 + w * 32 + n16;

    short8 afr[3][4];       // A ring, depth 3: [ring][rt*2+ks], rt in 0..1
    int nidr[2][KPH][2];    // nid ring: [phase parity][j][rt]

    auto issueA = [&](const int* nr, short8* af) {
        #pragma unroll
        for (int rt = 0; rt < 2; ++rt) {
            const unsigned short* r0 = fq + (size_t)nr[rt] * 64;
            af[rt * 2 + 0] = *(const short8*)(r0);
            af[rt * 2 + 1] = *(const short8*)(r0 + 32);
        }
    };

    floatx4 acc[2][4];
    #pragma unroll
    for (int rt = 0; rt < 2; ++rt)
        #pragma unroll
        for (int ct = 0; ct < 4; ++ct)
            acc[rt][ct] = (floatx4){0.f, 0.f, 0.f, 0.f};

    const uint4* wt4 = (const uint4*)Wt;

    // prologue: nid indices for phase 0
    #pragma unroll
    for (int j = 0; j < KPH; ++j) {
        nidr[0][j][0] = nbase[(size_t)j * NMT];
        nidr[0][j][1] = nbase[(size_t)j * NMT + 16];
    }

    for (int ph = 0; ph < 7; ++ph) {
        int k0 = ph * KPH;
        int cur = ph & 1;
        __syncthreads();   // previous phase's s_b fully consumed
        // stage B for this phase: 8 x 16 B per thread
        #pragma unroll
        for (int i = 0; i < KPH * 2; ++i)
            ((uint4*)s_b)[i * 256 + tid] = wt4[(size_t)k0 * 512 + i * 256 + tid];
        // prefetch next phase's nid indices (consumed next phase)
        if (ph < 6) {
            #pragma unroll
            for (int j = 0; j < KPH; ++j) {
                nidr[cur ^ 1][j][0] = nbase[(size_t)(k0 + KPH + j) * NMT];
                nidr[cur ^ 1][j][1] = nbase[(size_t)(k0 + KPH + j) * NMT + 16];
            }
        }
        // A prologue for this phase (drained by the barrier; ready at j=0)
        issueA(nidr[cur][0], afr[0]);
        issueA(nidr[cur][1], afr[1]);
        __syncthreads();

        #pragma unroll
        for (int j = 0; j < KPH; ++j) {
            if (j + 2 < KPH) issueA(nidr[cur][j + 2], afr[(j + 2) % 3]);
            __builtin_amdgcn_sched_barrier(0);   // A loads stay above MFMAs

            const unsigned short* bb = s_b + j * 4096;
            short8 bfr[8];
            #pragma unroll
            for (int fr = 0; fr < 8; ++fr)
                bfr[fr] = *(const short8*)(bb + fr * 512 + lane * 8);

            const short8* ac = afr[j % 3];
            #pragma unroll
            for (int ks = 0; ks < 2; ++ks)
                #pragma unroll
                for (int rt = 0; rt < 2; ++rt)
                    #pragma unroll
                    for (int ct = 0; ct < 4; ++ct)
                        acc[rt][ct] = __builtin_amdgcn_mfma_f32_16x16x32_bf16(
                            ac[rt * 2 + ks], bfr[ct * 2 + ks], acc[rt][ct], 0, 0, 0);
            __builtin_amdgcn_sched_barrier(0);   // MFMAs stay above next A loads
        }
    }

    // store bf16 conv output.  C/D layout: col = lane&15, row = quad*4 + reg
    #pragma unroll
    for (int rt = 0; rt < 2; ++rt) {
        int rbase = m0 + w * 32 + rt * 16 + quad * 4;
        #pragma unroll
        for (int rg = 0; rg < 4; ++rg) {
            int m = rbase + rg;
            if (m < NM) {
                #pragma unroll
                for (int ct = 0; ct < 4; ++ct)
                    out[(size_t)m * 64 + ct * 16 + n16] = f2bf(acc[rt][ct][rg]);
            }
        }
    }

    // BN stats from fp32 accumulators (pad rows gather only zero-row -> exact 0)
    float ps[4], pq[4];
    #pragma unroll
    for (int ct = 0; ct < 4; ++ct) { ps[ct] = 0.f; pq[ct] = 0.f; }
    #pragma unroll
    for (int rt = 0; rt < 2; ++rt)
        #pragma unroll
        for (int ct = 0; ct < 4; ++ct)
            #pragma unroll
            for (int rg = 0; rg < 4; ++rg) {
                float v = acc[rt][ct][rg];
                ps[ct] += v;
                pq[ct] += v * v;
            }
    #pragma unroll
    for (int ct = 0; ct < 4; ++ct) {
        ps[ct] += __shfl_xor(ps[ct], 16);
        ps[ct] += __shfl_xor(ps[ct], 32);
        pq[ct] += __shfl_xor(pq[ct], 16);
        pq[ct] += __shfl_xor(pq[ct], 32);
    }
    __syncthreads();
    float* red = (float*)s_b;
    if (lane < 16) {
        #pragma unroll
        for (int ct = 0; ct < 4; ++ct) {
            red[w * 64 + ct * 16 + n16]       = ps[ct];
            red[256 + w * 64 + ct * 16 + n16] = pq[ct];
        }
    }
    __syncthreads();
    if (tid < 64) {
        float ts = 0.f, tq = 0.f;
        #pragma unroll
        for (int ww = 0; ww < 4; ++ww) {
            ts += red[ww * 64 + tid];
            tq += red[256 + ww * 64 + tid];
        }
        atomicAdd(gsum + tid, ts);
        atomicAdd(gsq + tid, tq);
    }
}

// ---------------- BN apply + ReLU (bf16 -> bf16), coef computed inline ----------
__global__ void k_bnapply(const unsigned short* __restrict__ in,
                          const float* __restrict__ gsum, const float* __restrict__ gsq,
                          const float* __restrict__ gamma, const float* __restrict__ beta,
                          unsigned short* __restrict__ out) {
    int i = blockIdx.x * 256 + threadIdx.x;  // over NM*8 groups of 8 bf16
    if (i >= NM * 8) return;
    int c8 = (i & 7) * 8;
    float scv[8], shv[8];
    #pragma unroll
    for (int jj = 0; jj < 8; ++jj) {
        int c = c8 + jj;
        float mu = gsum[c] * (1.f / NM);
        float var = gsq[c] * (1.f / NM) - mu * mu;
        float s = gamma[c] * rsqrtf(var + EPSV);
        scv[jj] = s;
        shv[jj] = beta[c] - mu * s;
    }
    uint4 v = ((const uint4*)in)[i];
    unsigned int vv[4] = {v.x, v.y, v.z, v.w};
    unsigned int oo[4];
    #pragma unroll
    for (int j = 0; j < 4; ++j) {
        float lo = bf2f((unsigned short)(vv[j] & 0xffffu));
        float hi = bf2f((unsigned short)(vv[j] >> 16));
        lo = fmaxf(lo * scv[j * 2]     + shv[j * 2],     0.f);
        hi = fmaxf(hi * scv[j * 2 + 1] + shv[j * 2 + 1], 0.f);
        oo[j] = (unsigned int)f2bf(lo) | ((unsigned int)f2bf(hi) << 16);
    }
    uint4 o = {oo[0], oo[1], oo[2], oo[3]};
    ((uint4*)out)[i] = o;
}

// ---------------- keypoint sampling + fused BN2/ReLU + projection ----------------
__global__ __launch_bounds__(256) void k_sample(
    const float* __restrict__ kp, const float* __restrict__ query,
    const unsigned short* __restrict__ conv2,
    const float* __restrict__ gsum2, const float* __restrict__ gsq2,
    const float* __restrict__ g2, const float* __restrict__ b2,
    const int* __restrict__ grid, const int* __restrict__ fbp,
    const float* __restrict__ projW, const float* __restrict__ projB,
    float* __restrict__ out_fused, float* __restrict__ out_vi)
{
    __shared__ float s_pw[64 * 65];
    __shared__ float s_mean[4][64];
    __shared__ int   s_idx[4][8];

    int tid = threadIdx.x;
    for (int e = tid; e < 4096; e += 256) {
        int co = e >> 6, c = e & 63;
        s_pw[co * 65 + c] = projW[e];
    }

    int w = tid >> 6, lane = tid & 63;
    int row = blockIdx.x * 4 + w;   // < 16384
    int b = row >> 13;              // NN = 8192
    float mu = gsum2[lane] * (1.f / NM);
    float var = gsq2[lane] * (1.f / NM) - mu * mu;
    float sc = g2[lane] * rsqrtf(var + EPSV);
    float sh = b2[lane] - mu * sc;
    int fb = fbp[0];                // sorted id of original row 0
    __syncthreads();

    if (lane < 8) {
        int kk = lane;
        const float* kpp = kp + ((size_t)row * 8 + kk) * 3;
        int qx = min(max((int)(kpp[0] * 2.0f), 0), GX - 1);
        int qy = min(max((int)(kpp[1] * 2.0f), 0), GY - 1);
        int qz = min(max((int)(kpp[2] * 2.0f), 0), GZ - 1);
        s_idx[w][kk] = grid[((b * GX + qx) * GY + qy) * GZ + qz];
        float4 vi = make_float4((float)b, (float)qx, (float)qy, (float)qz);
        *(float4*)(out_vi + ((size_t)row * 8 + kk) * 4) = vi;
    }
    __syncthreads();

    float acc = 0.f;
    #pragma unroll
    for (int kk = 0; kk < 8; ++kk) {
        int gi = s_idx[w][kk];
        gi = gi < 0 ? fb : gi;
        float v = bf2f(conv2[(size_t)gi * 64 + lane]);
        acc += fmaxf(v * sc + sh, 0.f);      // fused BN2 + ReLU
    }
    float mean = acc * 0.125f + query[(size_t)row * 64 + lane];
    s_mean[w][lane] = mean;
    __syncthreads();

    float f = projB[lane];
    const float* pwr = s_pw + lane * 65;
    const float* mv = s_mean[w];
    #pragma unroll 8
    for (int c = 0; c < 64; ++c) f += mv[c] * pwr[c];
    out_fused[(size_t)row * 64 + lane] = f;
}

// ---------------- launch ----------------
extern "C" void kernel_launch(void* const* d_in, const int* in_sizes, int n_in,
                              void* d_out, int out_size, void* d_ws, size_t ws_size,
                              hipStream_t stream) {
    const float* keypoints = (const float*)d_in[0];
    const float* query     = (const float*)d_in[1];
    const float* vfeat     = (const float*)d_in[2];
    const int*   vcoords   = (const int*)d_in[3];
    const float* W1        = (const float*)d_in[4];
    const float* g1        = (const float*)d_in[5];
    const float* b1        = (const float*)d_in[6];
    const float* W2        = (const float*)d_in[7];
    const float* g2        = (const float*)d_in[8];
    const float* b2        = (const float*)d_in[9];
    const float* pW        = (const float*)d_in[10];
    const float* pb        = (const float*)d_in[11];

    char* ws = (char*)d_ws;
    int*            gold  = (int*)ws;                          // 2,097,152 B
    int*            gnew  = (int*)(ws + 2097152);              // 2,097,152 B
    float*          stats = (float*)(ws + 4194304);            // 2048 B
    int*            fbp   = (int*)(ws + 4196352);              // 256 B
    int*            bcnt  = (int*)(ws + 4196608);              // 8192 B
    int*            boff  = (int*)(ws + 4204800);              // 8192 B
    int*            perm  = (int*)(ws + 4212992);              // 800,000 B
    int*            scell = (int*)(ws + 5012992);              // 800,000 B
    unsigned short* Wt1   = (unsigned short*)(ws + 5812992);   // 229,376 B (28 k's)
    unsigned short* Wt2   = (unsigned short*)(ws + 6042368);   // 229,376 B
    unsigned short* featA = (unsigned short*)(ws + 6271744);   // (NM+1)*128 B -> 25,600,256
    int*            nidt  = (int*)(ws + 31872000);             // 28*NMT*4 = 22,478,848 B
    unsigned short* convo = (unsigned short*)(ws + 54350848);  // 25,600,000 B (ends ~80 MB)

    float* sum1 = stats,       *sq1 = stats + 64;
    float* sum2 = stats + 256, *sq2 = stats + 320;

    int initN = NCELLT + 512 + 64;
    k_init<<<(initN + 255) / 256, 256, 0, stream>>>(gold, stats, featA);
    k_scatter<<<(NM + 255) / 256, 256, 0, stream>>>(vcoords, gold);

    // spatial renumbering: count -> scan -> assign -> neighbor table (+fb)
    k_count<<<NCELLT / 256, 256, 0, stream>>>(gold, bcnt);
    k_scan2048<<<1, 256, 0, stream>>>(bcnt, boff);
    k_assign<<<NCELLT / 256, 256, 0, stream>>>(gold, boff, gnew, perm, scell);
    k_nbr<<<NMT / 256, 256, 0, stream>>>(scell, gnew, vcoords, nidt, fbp);

    // weights + features prep (merged)
    k_prep<<<56 + (NM * 8 + 255) / 256, 256, 0, stream>>>(W1, W2, vfeat, perm,
                                                          Wt1, Wt2, featA);

    k_conv<<<NBLK, 256, 0, stream>>>(featA, nidt, Wt1, convo, sum1, sq1);
    k_bnapply<<<(NM * 8 + 255) / 256, 256, 0, stream>>>(convo, sum1, sq1, g1, b1, featA);

    k_conv<<<NBLK, 256, 0, stream>>>(featA, nidt, Wt2, convo, sum2, sq2);

    float* out_fused = (float*)d_out;
    float* out_vi = out_fused + (size_t)NB * NN * NC;  // 1,048,576 floats
    k_sample<<<(NB * NN) / 4, 256, 0, stream>>>(keypoints, query, convo, sum2, sq2, g2, b2,
                                                gnew, fbp, pW, pb, out_fused, out_vi);
}